// Round 14
// baseline (328.254 us; speedup 1.0000x reference)
//
#include <hip/hip_runtime.h>
#include <hip/hip_bf16.h>
#include <math.h>

#define NN 40000
#define NE 640000

typedef __attribute__((ext_vector_type(8))) short short8;
typedef __attribute__((ext_vector_type(8))) unsigned short u16x8;
typedef __attribute__((ext_vector_type(4))) float f32x4;
typedef _Float16 h16x2 __attribute__((ext_vector_type(2)));

#define WBLOCKS 547   // weight-prep blocks
#define GBLOCKS 625   // row blocks (NN/64)
#define NCO 157       // coarse buckets (dst>>8)
#define P1B 160       // pass1/pass2 blocks
#define EPB 4000      // edges per pass1/2 block

#if __has_builtin(__builtin_amdgcn_fdot2)
#define HAS_FDOT2 1
#else
#define HAS_FDOT2 0
#endif

__device__ __forceinline__ float gelu_tanh(float x) {
    float u = 0.7978845608028654f * (x + 0.044715f * x * x * x);
    float a = 2.885390081777927f * u;          // 2*log2(e)*u
    a = fminf(fmaxf(a, -120.f), 120.f);
    float E = exp2f(a);
    return x * E / (E + 1.0f);
}

__device__ __forceinline__ unsigned short f2bf(float v) {
    __hip_bfloat16 h = __float2bfloat16(v);
    return *reinterpret_cast<unsigned short*>(&h);
}

__device__ __forceinline__ unsigned short f2h(float v) {
    union { _Float16 h; unsigned short u; } c;
    c.h = (_Float16)v;
    return c.u;
}

__device__ __forceinline__ float bf2f(unsigned short u) {
    union { unsigned int i; float f; } c;
    c.i = ((unsigned int)u) << 16;
    return c.f;
}

__device__ __forceinline__ void unpack8(u16x8 u, float* f) {
    union { u16x8 v; unsigned int d[4]; } c; c.v = u;
    #pragma unroll
    for (int i = 0; i < 4; ++i) {
        union { unsigned int i_; float f_; } lo, hi;
        lo.i_ = c.d[i] << 16;
        hi.i_ = c.d[i] & 0xffff0000u;
        f[2 * i] = lo.f_;
        f[2 * i + 1] = hi.f_;
    }
}

union kv8 { u16x8 u; h16x2 p[4]; _Float16 h[8]; };
union frag8 { short8 s; unsigned short u[8]; u16x8 v; };

// ---------------- prep: weights (blocks 0..546) + coarse hist pass1 (rest) ------
__global__ __launch_bounds__(256) void prep_kernel(
    const float* __restrict__ Wq, const float* __restrict__ bq,
    const float* __restrict__ Wk, const float* __restrict__ bk,
    const float* __restrict__ a_rel,
    const float* __restrict__ Wv, const float* __restrict__ bv,
    const float* __restrict__ m_rel,
    const float* __restrict__ p_rel,
    const float* __restrict__ aW, const float* __restrict__ fcW,
    unsigned short* __restrict__ BfT, float* __restrict__ biasf,
    unsigned short* __restrict__ aWT, unsigned short* __restrict__ fcWT,
    const int* __restrict__ eidx, int* __restrict__ Hmat,
    int* __restrict__ coarseTot)
{
    if (blockIdx.x >= WBLOCKS) {
        __shared__ int chist[NCO];
        int b = blockIdx.x - WBLOCKS;
        int t = threadIdx.x;
        if (t < NCO) chist[t] = 0;
        __syncthreads();
        int base = b * EPB;
        for (int e = base + t; e < base + EPB; e += 256)
            atomicAdd(&chist[eidx[NE + e] >> 8], 1);
        __syncthreads();
        if (t < NCO) {
            Hmat[t * P1B + b] = chist[t];
            atomicAdd(&coarseTot[t], chist[t]);
        }
        return;
    }
    int idx = blockIdx.x * 256 + threadIdx.x;
    if (idx < 2 * 129 * 384) {
        int l = idx / (129 * 384);
        int j = idx - l * (129 * 384);
        int r = j / 384;
        int col = j - r * 384;
        const float* Wq_l = Wq + l * 16384;
        const float* Wk_l = Wk + l * 16384;
        const float* Wv_l = Wv + l * 16384;
        const float* ar_l = a_rel + l * 2048;
        const float* mr_l = m_rel + l * 2048;
        float val;
        if (col < 128) {
            val = (r < 128) ? Wq_l[r * 128 + col] : bq[l * 128 + col];
        } else if (col < 256) {
            int cc = col - 128; int h = cc >> 4; int eo = cc & 15;
            float scale = p_rel[l * 8 + h] * 0.25f * 1.4426950408889634f;
            float s = 0.f;
            #pragma unroll
            for (int d = 0; d < 16; ++d) {
                float w = (r < 128) ? Wk_l[r * 128 + h * 16 + d] : bk[l * 128 + h * 16 + d];
                s += w * ar_l[h * 256 + d * 16 + eo];
            }
            val = s * scale;
        } else {
            int cc = col - 256; int h = cc >> 4; int eo = cc & 15;
            float s = 0.f;
            #pragma unroll
            for (int d = 0; d < 16; ++d) {
                float w = (r < 128) ? Wv_l[r * 128 + h * 16 + d] : bv[l * 128 + h * 16 + d];
                s += w * mr_l[h * 256 + d * 16 + eo];
            }
            val = s;
        }
        if (r < 128) BfT[(size_t)l * 49152 + (size_t)col * 128 + r] = f2bf(val);
        else         biasf[l * 384 + col] = val;
    } else if (idx < 2 * 129 * 384 + 2 * 16384) {
        int i = idx - 2 * 129 * 384;
        int l = i >> 14; int j = i & 16383;
        int r = j >> 7, c = j & 127;
        aWT[(size_t)l * 16384 + (size_t)c * 128 + r] = f2bf(aW[(size_t)l * 16384 + r * 128 + c]);
    } else {
        int i = idx - (2 * 129 * 384 + 2 * 16384);
        int c = i >> 7, r = i & 127;
        fcWT[(size_t)c * 128 + r] = f2bf(fcW[(size_t)r * 64 + c]);
    }
}

// ---------------- tiny scan over 157 coarse totals -------------------------------
__global__ __launch_bounds__(256) void scan157_kernel(
    const int* __restrict__ coarseTot, int* __restrict__ bucketBase,
    int* __restrict__ cursor)
{
    __shared__ int s[256];
    int t = threadIdx.x;
    int v = (t < NCO) ? coarseTot[t] : 0;
    s[t] = v;
    __syncthreads();
    #pragma unroll
    for (int off = 1; off < 256; off <<= 1) {
        int u = (t >= off) ? s[t - off] : 0;
        __syncthreads();
        s[t] += u;
        __syncthreads();
    }
    int excl = s[t] - v;
    if (t < NCO) { bucketBase[t] = excl; cursor[t] = excl; }
    if (t == 0) bucketBase[NCO] = NE;
}

// ---------------- pass 2: coarse bucketing; block reserves range via atomics ----
__global__ __launch_bounds__(256) void pass2_kernel(
    const int* __restrict__ eidx, const int* __restrict__ Hmat,
    int* __restrict__ cursor, int* __restrict__ ebuk)
{
    __shared__ int cur[NCO];
    int b = blockIdx.x, t = threadIdx.x;
    if (t < NCO) {
        int cnt = Hmat[t * P1B + b];
        cur[t] = atomicAdd(&cursor[t], cnt);
    }
    __syncthreads();
    int base = b * EPB;
    for (int e = base + t; e < base + EPB; e += 256) {
        int s = eidx[e];
        int d = eidx[NE + e];
        int pos = atomicAdd(&cur[d >> 8], 1);
        ebuk[pos] = ((d & 255) << 16) | s;
    }
}

// ---- qkv0 GEMM (blocks 0..624) + CSR pass 3 (blocks 625..781) -------------------
// qb rows: f16 [NN][128].  kvb rows: [k f16 (128) | v bf16 (128)], 512 B.
__global__ __launch_bounds__(256) void qkv0_p3_kernel(
    const float* __restrict__ Af, const unsigned short* __restrict__ BT,
    const float* __restrict__ bias,
    unsigned short* __restrict__ qb, unsigned short* __restrict__ kvb,
    const int* __restrict__ bucketBase, const int* __restrict__ ebuk,
    int* __restrict__ deg, int* __restrict__ offs, int* __restrict__ srcSorted)
{
    if (blockIdx.x >= GBLOCKS) {
        __shared__ int hist[256], loffs[256], cur[256];
        int c = blockIdx.x - GBLOCKS;
        int t = threadIdx.x;
        int base = bucketBase[c];
        int end = bucketBase[c + 1];
        hist[t] = 0;
        __syncthreads();
        for (int i = base + t; i < end; i += 256)
            atomicAdd(&hist[ebuk[i] >> 16], 1);
        __syncthreads();
        int v = hist[t];
        loffs[t] = v;
        __syncthreads();
        #pragma unroll
        for (int off = 1; off < 256; off <<= 1) {
            int u = (t >= off) ? loffs[t - off] : 0;
            __syncthreads();
            loffs[t] += u;
            __syncthreads();
        }
        int excl = loffs[t] - v;
        int n = c * 256 + t;
        if (n < NN) { deg[n] = v; offs[n] = base + excl; }
        cur[t] = excl;
        __syncthreads();
        for (int i = base + t; i < end; i += 256) {
            int p = ebuk[i];
            int pos = atomicAdd(&cur[p >> 16], 1);
            srcSorted[base + pos] = p & 0xffff;
        }
        return;
    }
    __shared__ unsigned short Bs[64][136];
    int t = threadIdx.x;
    int row0 = blockIdx.x * 64;
    int w = t >> 6;
    int lr = t & 15;
    int quad = (t & 63) >> 4;
    int row = row0 + w * 16 + lr;

    frag8 af[4];
    {
        const float* ap = Af + (size_t)row * 128 + quad * 8;
        #pragma unroll
        for (int kc = 0; kc < 4; ++kc) {
            float4 a0 = *(const float4*)(ap + kc * 32);
            float4 a1 = *(const float4*)(ap + kc * 32 + 4);
            af[kc].u[0] = f2bf(a0.x); af[kc].u[1] = f2bf(a0.y);
            af[kc].u[2] = f2bf(a0.z); af[kc].u[3] = f2bf(a0.w);
            af[kc].u[4] = f2bf(a1.x); af[kc].u[5] = f2bf(a1.y);
            af[kc].u[6] = f2bf(a1.z); af[kc].u[7] = f2bf(a1.w);
        }
    }

    #pragma unroll
    for (int ct = 0; ct < 6; ++ct) {
        if (ct) __syncthreads();
        #pragma unroll
        for (int i = 0; i < 4; ++i) {
            int idx = t + i * 256;
            int r = idx >> 4;
            int c8 = (idx & 15) * 8;
            *(u16x8*)(&Bs[r][c8]) = *(const u16x8*)(BT + (size_t)(ct * 64 + r) * 128 + c8);
        }
        __syncthreads();
        f32x4 acc[4] = {{0.f,0.f,0.f,0.f},{0.f,0.f,0.f,0.f},
                        {0.f,0.f,0.f,0.f},{0.f,0.f,0.f,0.f}};
        #pragma unroll
        for (int kc = 0; kc < 4; ++kc) {
            #pragma unroll
            for (int n4 = 0; n4 < 4; ++n4) {
                short8 bfr = *(const short8*)(&Bs[n4 * 16 + lr][kc * 32 + quad * 8]);
                acc[n4] = __builtin_amdgcn_mfma_f32_16x16x32_bf16(bfr, af[kc].s, acc[n4], 0, 0, 0);
            }
        }
        unsigned short* dst = (ct < 2) ? (qb + (size_t)row * 128 + (ct & 1) * 64)
                                       : (kvb + (size_t)row * 256 + (ct - 2) * 64);
        #pragma unroll
        for (int n4 = 0; n4 < 4; ++n4) {
            int colb = n4 * 16 + quad * 4;
            float4 bv = *(const float4*)(bias + ct * 64 + colb);
            ushort4 o;
            if (ct >= 4) {
                o.x = f2bf(acc[n4][0] + bv.x);
                o.y = f2bf(acc[n4][1] + bv.y);
                o.z = f2bf(acc[n4][2] + bv.z);
                o.w = f2bf(acc[n4][3] + bv.w);
            } else {
                o.x = f2h(acc[n4][0] + bv.x);
                o.y = f2h(acc[n4][1] + bv.y);
                o.z = f2h(acc[n4][2] + bv.z);
                o.w = f2h(acc[n4][3] + bv.w);
            }
            *(ushort4*)(dst + colb) = o;
        }
    }
}

// ---- mega: aggregate (into LDS) + out-GEMM + {next-layer QKV | fc} --------------
// LAYER 0: Hprev = x (f32), stores hb + qbOut/kvbOut.  LAYER 1: Hprev = hb (bf16),
// h stays in LDS, fc -> outF.
template <int LAYER>
__global__ __launch_bounds__(256) void mega_kernel(
    const unsigned short* __restrict__ qbIn, const unsigned short* __restrict__ kvbIn,
    const int* __restrict__ deg, const int* __restrict__ offs,
    const int* __restrict__ srcSorted,
    const unsigned short* __restrict__ aWT_l, const float* __restrict__ ab_l,
    const float* __restrict__ skip_l,
    const float* __restrict__ HprevF, const unsigned short* __restrict__ HprevB,
    unsigned short* __restrict__ hb_out,
    const unsigned short* __restrict__ W2T, const float* __restrict__ bias2,
    unsigned short* __restrict__ qbOut, unsigned short* __restrict__ kvbOut,
    float* __restrict__ outF)
{
    __shared__ unsigned short As[64][136];
    __shared__ unsigned short Bs[2][64][136];
    int t = threadIdx.x;
    int row0 = blockIdx.x * 64;
    int w = t >> 6;
    int lane = t & 63;
    int es = lane >> 3;
    int h = lane & 7;
    int lr = lane & 15;
    int quad = lane >> 4;
    int row = row0 + w * 16 + lr;

    // preload both out-B tiles (aWT)
    #pragma unroll
    for (int i = 0; i < 8; ++i) {
        int idx = t + i * 256;
        int tile = idx >> 10;
        int j = idx & 1023;
        int r = j >> 4;
        int c8 = (j & 15) * 8;
        *(u16x8*)(&Bs[tile][r][c8]) = *(const u16x8*)(aWT_l + (size_t)(tile * 64 + r) * 128 + c8);
    }
    __syncthreads();

    // ---- aggregate phase: wave w handles nodes row0+w*16 .. +15 ----
    for (int ii = 0; ii < 16; ++ii) {
        int n = row0 + w * 16 + ii;
#if HAS_FDOT2
        h16x2 q2[8];
        {
            const h16x2* qp = (const h16x2*)(qbIn + (size_t)n * 128 + h * 16);
            #pragma unroll
            for (int j = 0; j < 8; ++j) q2[j] = qp[j];
        }
#else
        float q[16];
        {
            kv8 a, b;
            a.u = *(const u16x8*)(qbIn + (size_t)n * 128 + h * 16);
            b.u = *(const u16x8*)(qbIn + (size_t)n * 128 + h * 16 + 8);
            #pragma unroll
            for (int j = 0; j < 8; ++j) { q[j] = (float)a.h[j]; q[8 + j] = (float)b.h[j]; }
        }
#endif
        float acc[16];
        #pragma unroll
        for (int j = 0; j < 16; ++j) acc[j] = 0.f;
        float den = 0.f;

        int start = offs[n];
        int d = deg[n];
        if (d > 0) {
            int ng = (d + 7) >> 3;
            int lastIdx = start + d - 1;
            kv8 ka0, ka1; u16x8 vA0, vA1;
            kv8 kB0, kB1; u16x8 vB0, vB1;
            {
                int i0 = start + es; if (i0 > lastIdx) i0 = lastIdx;
                const unsigned short* p = kvbIn + (size_t)srcSorted[i0] * 256 + h * 16;
                ka0.u = *(const u16x8*)p;        ka1.u = *(const u16x8*)(p + 8);
                vA0 = *(const u16x8*)(p + 128);  vA1 = *(const u16x8*)(p + 136);
            }
            kB0 = ka0; kB1 = ka1; vB0 = vA0; vB1 = vA1;
            if (ng > 1) {
                int i1 = start + 8 + es; if (i1 > lastIdx) i1 = lastIdx;
                const unsigned short* p = kvbIn + (size_t)srcSorted[i1] * 256 + h * 16;
                kB0.u = *(const u16x8*)p;        kB1.u = *(const u16x8*)(p + 8);
                vB0 = *(const u16x8*)(p + 128);  vB1 = *(const u16x8*)(p + 136);
            }
            for (int g = 0; g < ng; ++g) {
                kv8 kC0 = ka0, kC1 = ka1; u16x8 vC0 = vA0, vC1 = vA1;
                if (g + 2 < ng) {
                    int ni = start + (g + 2) * 8 + es; if (ni > lastIdx) ni = lastIdx;
                    const unsigned short* p = kvbIn + (size_t)srcSorted[ni] * 256 + h * 16;
                    kC0.u = *(const u16x8*)p;        kC1.u = *(const u16x8*)(p + 8);
                    vC0 = *(const u16x8*)(p + 128);  vC1 = *(const u16x8*)(p + 136);
                }
                float pdot = 0.f;
#if HAS_FDOT2
                #pragma unroll
                for (int j = 0; j < 4; ++j) pdot = __builtin_amdgcn_fdot2(ka0.p[j], q2[j], pdot, false);
                #pragma unroll
                for (int j = 0; j < 4; ++j) pdot = __builtin_amdgcn_fdot2(ka1.p[j], q2[4 + j], pdot, false);
#else
                #pragma unroll
                for (int j = 0; j < 8; ++j) pdot = fmaf((float)ka0.h[j], q[j], pdot);
                #pragma unroll
                for (int j = 0; j < 8; ++j) pdot = fmaf((float)ka1.h[j], q[8 + j], pdot);
#endif
                float ev = (g * 8 + es < d) ? exp2f(pdot) : 0.f;
                den += ev;
                float vf[16];
                unpack8(vA0, vf); unpack8(vA1, vf + 8);
                #pragma unroll
                for (int j = 0; j < 16; ++j) acc[j] = fmaf(vf[j], ev, acc[j]);
                ka0 = kB0; ka1 = kB1; vA0 = vB0; vA1 = vB1;
                kB0 = kC0; kB1 = kC1; vB0 = vC0; vB1 = vC1;
            }
        }
        #pragma unroll
        for (int m = 8; m < 64; m <<= 1) {
            den += __shfl_xor(den, m, 64);
            #pragma unroll
            for (int j = 0; j < 16; ++j) acc[j] += __shfl_xor(acc[j], m, 64);
        }
        if (es == 0) {
            float wgt = 1.f / (den + 1e-16f);
            u16x8 o0, o1;
            #pragma unroll
            for (int j = 0; j < 8; ++j) {
                o0[j] = f2bf(gelu_tanh(acc[j] * wgt));
                o1[j] = f2bf(gelu_tanh(acc[j + 8] * wgt));
            }
            *(u16x8*)(&As[w * 16 + ii][h * 16]) = o0;
            *(u16x8*)(&As[w * 16 + ii][h * 16 + 8]) = o1;
        }
    }
    // no barrier: As rows + Bs tiles wave-local reads from here

    // ---- out-GEMM: h = relu(beta*(gelu(agg)@aWT + ab) + (1-beta)*Hprev) ----
    float sv = skip_l[0];
    float beta = 1.f / (1.f + expf(-sv));
    float omb = 1.f - beta;

    f32x4 hacc[2][4];
    #pragma unroll
    for (int ct = 0; ct < 2; ++ct) {
        #pragma unroll
        for (int n4 = 0; n4 < 4; ++n4) hacc[ct][n4] = (f32x4){0.f,0.f,0.f,0.f};
        #pragma unroll
        for (int kc = 0; kc < 4; ++kc) {
            short8 afr = *(const short8*)(&As[w * 16 + lr][kc * 32 + quad * 8]);
            #pragma unroll
            for (int n4 = 0; n4 < 4; ++n4) {
                short8 bfr = *(const short8*)(&Bs[ct][n4 * 16 + lr][kc * 32 + quad * 8]);
                hacc[ct][n4] = __builtin_amdgcn_mfma_f32_16x16x32_bf16(bfr, afr, hacc[ct][n4], 0, 0, 0);
            }
        }
    }
    #pragma unroll
    for (int ct = 0; ct < 2; ++ct) {
        #pragma unroll
        for (int n4 = 0; n4 < 4; ++n4) {
            int colb = ct * 64 + n4 * 16 + quad * 4;
            float4 bv = *(const float4*)(ab_l + colb);
            float hp[4];
            if (LAYER == 0) {
                float4 h4 = *(const float4*)(HprevF + (size_t)row * 128 + colb);
                hp[0] = h4.x; hp[1] = h4.y; hp[2] = h4.z; hp[3] = h4.w;
            } else {
                ushort4 h4 = *(const ushort4*)(HprevB + (size_t)row * 128 + colb);
                hp[0] = bf2f(h4.x); hp[1] = bf2f(h4.y); hp[2] = bf2f(h4.z); hp[3] = bf2f(h4.w);
            }
            ushort4 o;
            o.x = f2bf(fmaxf(beta * (hacc[ct][n4][0] + bv.x) + omb * hp[0], 0.f));
            o.y = f2bf(fmaxf(beta * (hacc[ct][n4][1] + bv.y) + omb * hp[1], 0.f));
            o.z = f2bf(fmaxf(beta * (hacc[ct][n4][2] + bv.z) + omb * hp[2], 0.f));
            o.w = f2bf(fmaxf(beta * (hacc[ct][n4][3] + bv.w) + omb * hp[3], 0.f));
            *(ushort4*)(&As[w * 16 + lr][colb]) = o;   // wave-local row
            if (LAYER == 0) *(ushort4*)(hb_out + (size_t)row * 128 + colb) = o;
        }
    }

    // ---- phase 2 ----
    if (LAYER == 0) {
        #pragma unroll
        for (int ct = 0; ct < 6; ++ct) {
            __syncthreads();
            #pragma unroll
            for (int i = 0; i < 4; ++i) {
                int idx = t + i * 256;
                int r = idx >> 4;
                int c8 = (idx & 15) * 8;
                *(u16x8*)(&Bs[ct & 1][r][c8]) =
                    *(const u16x8*)(W2T + (size_t)(ct * 64 + r) * 128 + c8);
            }
            __syncthreads();
            f32x4 acc[4] = {{0.f,0.f,0.f,0.f},{0.f,0.f,0.f,0.f},
                            {0.f,0.f,0.f,0.f},{0.f,0.f,0.f,0.f}};
            #pragma unroll
            for (int kc = 0; kc < 4; ++kc) {
                short8 afr = *(const short8*)(&As[w * 16 + lr][kc * 32 + quad * 8]);
                #pragma unroll
                for (int n4 = 0; n4 < 4; ++n4) {
                    short8 bfr = *(const short8*)(&Bs[ct & 1][n4 * 16 + lr][kc * 32 + quad * 8]);
                    acc[n4] = __builtin_amdgcn_mfma_f32_16x16x32_bf16(bfr, afr, acc[n4], 0, 0, 0);
                }
            }
            unsigned short* dst = (ct < 2) ? (qbOut + (size_t)row * 128 + (ct & 1) * 64)
                                           : (kvbOut + (size_t)row * 256 + (ct - 2) * 64);
            #pragma unroll
            for (int n4 = 0; n4 < 4; ++n4) {
                int colb = n4 * 16 + quad * 4;
                float4 bv = *(const float4*)(bias2 + ct * 64 + colb);
                ushort4 o;
                if (ct >= 4) {
                    o.x = f2bf(acc[n4][0] + bv.x);
                    o.y = f2bf(acc[n4][1] + bv.y);
                    o.z = f2bf(acc[n4][2] + bv.z);
                    o.w = f2bf(acc[n4][3] + bv.w);
                } else {
                    o.x = f2h(acc[n4][0] + bv.x);
                    o.y = f2h(acc[n4][1] + bv.y);
                    o.z = f2h(acc[n4][2] + bv.z);
                    o.w = f2h(acc[n4][3] + bv.w);
                }
                *(ushort4*)(dst + colb) = o;
            }
        }
    } else {
        __syncthreads();
        #pragma unroll
        for (int i = 0; i < 4; ++i) {
            int idx = t + i * 256;
            int r = idx >> 4;
            int c8 = (idx & 15) * 8;
            *(u16x8*)(&Bs[0][r][c8]) = *(const u16x8*)(W2T + (size_t)r * 128 + c8);
        }
        __syncthreads();
        f32x4 acc[4] = {{0.f,0.f,0.f,0.f},{0.f,0.f,0.f,0.f},
                        {0.f,0.f,0.f,0.f},{0.f,0.f,0.f,0.f}};
        #pragma unroll
        for (int kc = 0; kc < 4; ++kc) {
            short8 afr = *(const short8*)(&As[w * 16 + lr][kc * 32 + quad * 8]);
            #pragma unroll
            for (int n4 = 0; n4 < 4; ++n4) {
                short8 bfr = *(const short8*)(&Bs[0][n4 * 16 + lr][kc * 32 + quad * 8]);
                acc[n4] = __builtin_amdgcn_mfma_f32_16x16x32_bf16(bfr, afr, acc[n4], 0, 0, 0);
            }
        }
        #pragma unroll
        for (int n4 = 0; n4 < 4; ++n4) {
            int colb = n4 * 16 + quad * 4;
            float4 bv = *(const float4*)(bias2 + colb);
            float4 o;
            o.x = acc[n4][0] + bv.x;
            o.y = acc[n4][1] + bv.y;
            o.z = acc[n4][2] + bv.z;
            o.w = acc[n4][3] + bv.w;
            *(float4*)(outF + (size_t)row * 64 + colb) = o;
        }
    }
}

extern "C" void kernel_launch(void* const* d_in, const int* in_sizes, int n_in,
                              void* d_out, int out_size, void* d_ws, size_t ws_size,
                              hipStream_t stream) {
    const float* x     = (const float*)d_in[0];
    const int*   eidx  = (const int*)d_in[1];
    const float* Wk    = (const float*)d_in[2];
    const float* bk    = (const float*)d_in[3];
    const float* Wq    = (const float*)d_in[4];
    const float* bq    = (const float*)d_in[5];
    const float* Wv    = (const float*)d_in[6];
    const float* bv    = (const float*)d_in[7];
    const float* a_rel = (const float*)d_in[8];
    const float* m_rel = (const float*)d_in[9];
    const float* p_rel = (const float*)d_in[10];
    const float* skip  = (const float*)d_in[11];
    const float* aW    = (const float*)d_in[12];
    const float* ab    = (const float*)d_in[13];
    const float* fcW   = (const float*)d_in[14];
    const float* fcb   = (const float*)d_in[15];
    float* out = (float*)d_out;

    float* biasf = (float*)d_ws;                              // 2*384
    unsigned short* hb   = (unsigned short*)(biasf + 768);    // NN*128
    unsigned short* qb0  = hb + (size_t)NN * 128;             // NN*128 (f16)
    unsigned short* kvb0 = qb0 + (size_t)NN * 128;            // NN*256
    unsigned short* qb1  = kvb0 + (size_t)NN * 256;           // NN*128
    unsigned short* kvb1 = qb1 + (size_t)NN * 128;            // NN*256
    unsigned short* BfT  = kvb1 + (size_t)NN * 256;           // 2*384*128
    unsigned short* aWT  = BfT + 2 * 384 * 128;               // 2*128*128
    unsigned short* fcWT = aWT + 2 * 128 * 128;               // 64*128
    int* deg        = (int*)(fcWT + 64 * 128);                // NN
    int* offs       = deg + NN;                               // NN
    int* Hmat       = offs + NN;                              // NCO*P1B
    int* coarseTot  = Hmat + NCO * P1B;                       // NCO
    int* bucketBase = coarseTot + NCO;                        // NCO+1
    int* cursor     = bucketBase + NCO + 1;                   // NCO
    int* ebuk       = cursor + NCO;                           // NE
    int* srcSorted  = ebuk + NE;                              // NE

    hipMemsetAsync(coarseTot, 0, NCO * sizeof(int), stream);
    prep_kernel<<<WBLOCKS + P1B, 256, 0, stream>>>(
        Wq, bq, Wk, bk, a_rel, Wv, bv, m_rel, p_rel, aW, fcW,
        BfT, biasf, aWT, fcWT, eidx, Hmat, coarseTot);
    scan157_kernel<<<1, 256, 0, stream>>>(coarseTot, bucketBase, cursor);
    pass2_kernel<<<P1B, 256, 0, stream>>>(eidx, Hmat, cursor, ebuk);

    // layer 0 QKV + CSR pass 3
    qkv0_p3_kernel<<<GBLOCKS + NCO, 256, 0, stream>>>(
        x, BfT, biasf, qb0, kvb0, bucketBase, ebuk, deg, offs, srcSorted);

    // mega layer 0: agg + out (Hprev=x) + QKV(layer1) -> qb1/kvb1, hb
    mega_kernel<0><<<GBLOCKS, 256, 0, stream>>>(
        qb0, kvb0, deg, offs, srcSorted, aWT, ab, skip, x, nullptr, hb,
        BfT + 49152, biasf + 384, qb1, kvb1, nullptr);

    // mega layer 1: agg + out (Hprev=hb) + fc -> out
    mega_kernel<1><<<GBLOCKS, 256, 0, stream>>>(
        qb1, kvb1, deg, offs, srcSorted, aWT + 16384, ab + 128, skip + 1,
        nullptr, hb, nullptr, fcWT, fcb, nullptr, nullptr, out);
}

// Round 15
// 277.166 us; speedup vs baseline: 1.1843x; 1.1843x over previous
//
#include <hip/hip_runtime.h>
#include <hip/hip_bf16.h>
#include <math.h>

#define NN 40000
#define NE 640000

typedef __attribute__((ext_vector_type(8))) short short8;
typedef __attribute__((ext_vector_type(8))) unsigned short u16x8;
typedef __attribute__((ext_vector_type(4))) float f32x4;
typedef _Float16 h16x2 __attribute__((ext_vector_type(2)));

#define WBLOCKS 547   // weight-prep blocks
#define GBLOCKS 625   // row blocks (NN/64)
#define NCO 157       // coarse buckets (dst>>8)
#define P1B 160       // pass1/pass2 blocks
#define EPB 4000      // edges per pass1/2 block

#if __has_builtin(__builtin_amdgcn_fdot2)
#define HAS_FDOT2 1
#else
#define HAS_FDOT2 0
#endif

__device__ __forceinline__ float gelu_tanh(float x) {
    float u = 0.7978845608028654f * (x + 0.044715f * x * x * x);
    float a = 2.885390081777927f * u;          // 2*log2(e)*u
    a = fminf(fmaxf(a, -120.f), 120.f);
    float E = exp2f(a);
    return x * E / (E + 1.0f);
}

__device__ __forceinline__ unsigned short f2bf(float v) {
    __hip_bfloat16 h = __float2bfloat16(v);
    return *reinterpret_cast<unsigned short*>(&h);
}

__device__ __forceinline__ unsigned short f2h(float v) {
    union { _Float16 h; unsigned short u; } c;
    c.h = (_Float16)v;
    return c.u;
}

__device__ __forceinline__ float bf2f(unsigned short u) {
    union { unsigned int i; float f; } c;
    c.i = ((unsigned int)u) << 16;
    return c.f;
}

__device__ __forceinline__ void unpack8(u16x8 u, float* f) {
    union { u16x8 v; unsigned int d[4]; } c; c.v = u;
    #pragma unroll
    for (int i = 0; i < 4; ++i) {
        union { unsigned int i_; float f_; } lo, hi;
        lo.i_ = c.d[i] << 16;
        hi.i_ = c.d[i] & 0xffff0000u;
        f[2 * i] = lo.f_;
        f[2 * i + 1] = hi.f_;
    }
}

union kv8 { u16x8 u; h16x2 p[4]; _Float16 h[8]; };
union frag8 { short8 s; unsigned short u[8]; u16x8 v; };

// ---------------- prep: weights (blocks 0..546) + coarse hist pass1 (rest) ------
__global__ __launch_bounds__(256) void prep_kernel(
    const float* __restrict__ Wq, const float* __restrict__ bq,
    const float* __restrict__ Wk, const float* __restrict__ bk,
    const float* __restrict__ a_rel,
    const float* __restrict__ Wv, const float* __restrict__ bv,
    const float* __restrict__ m_rel,
    const float* __restrict__ p_rel,
    const float* __restrict__ aW, const float* __restrict__ fcW,
    unsigned short* __restrict__ BfT, float* __restrict__ biasf,
    unsigned short* __restrict__ aWT, unsigned short* __restrict__ fcWT,
    const int* __restrict__ eidx, int* __restrict__ Hmat,
    int* __restrict__ coarseTot)
{
    if (blockIdx.x >= WBLOCKS) {
        __shared__ int chist[NCO];
        int b = blockIdx.x - WBLOCKS;
        int t = threadIdx.x;
        if (t < NCO) chist[t] = 0;
        __syncthreads();
        int base = b * EPB;
        for (int e = base + t; e < base + EPB; e += 256)
            atomicAdd(&chist[eidx[NE + e] >> 8], 1);
        __syncthreads();
        if (t < NCO) {
            Hmat[t * P1B + b] = chist[t];
            atomicAdd(&coarseTot[t], chist[t]);
        }
        return;
    }
    int idx = blockIdx.x * 256 + threadIdx.x;
    if (idx < 2 * 129 * 384) {
        int l = idx / (129 * 384);
        int j = idx - l * (129 * 384);
        int r = j / 384;
        int col = j - r * 384;
        const float* Wq_l = Wq + l * 16384;
        const float* Wk_l = Wk + l * 16384;
        const float* Wv_l = Wv + l * 16384;
        const float* ar_l = a_rel + l * 2048;
        const float* mr_l = m_rel + l * 2048;
        float val;
        if (col < 128) {
            val = (r < 128) ? Wq_l[r * 128 + col] : bq[l * 128 + col];
        } else if (col < 256) {
            int cc = col - 128; int h = cc >> 4; int eo = cc & 15;
            float scale = p_rel[l * 8 + h] * 0.25f * 1.4426950408889634f;
            float s = 0.f;
            #pragma unroll
            for (int d = 0; d < 16; ++d) {
                float w = (r < 128) ? Wk_l[r * 128 + h * 16 + d] : bk[l * 128 + h * 16 + d];
                s += w * ar_l[h * 256 + d * 16 + eo];
            }
            val = s * scale;
        } else {
            int cc = col - 256; int h = cc >> 4; int eo = cc & 15;
            float s = 0.f;
            #pragma unroll
            for (int d = 0; d < 16; ++d) {
                float w = (r < 128) ? Wv_l[r * 128 + h * 16 + d] : bv[l * 128 + h * 16 + d];
                s += w * mr_l[h * 256 + d * 16 + eo];
            }
            val = s;
        }
        if (r < 128) BfT[(size_t)l * 49152 + (size_t)col * 128 + r] = f2bf(val);
        else         biasf[l * 384 + col] = val;
    } else if (idx < 2 * 129 * 384 + 2 * 16384) {
        int i = idx - 2 * 129 * 384;
        int l = i >> 14; int j = i & 16383;
        int r = j >> 7, c = j & 127;
        aWT[(size_t)l * 16384 + (size_t)c * 128 + r] = f2bf(aW[(size_t)l * 16384 + r * 128 + c]);
    } else {
        int i = idx - (2 * 129 * 384 + 2 * 16384);
        int c = i >> 7, r = i & 127;
        fcWT[(size_t)c * 128 + r] = f2bf(fcW[(size_t)r * 64 + c]);
    }
}

// ---------------- tiny scan over 157 coarse totals -------------------------------
__global__ __launch_bounds__(256) void scan157_kernel(
    const int* __restrict__ coarseTot, int* __restrict__ bucketBase,
    int* __restrict__ cursor)
{
    __shared__ int s[256];
    int t = threadIdx.x;
    int v = (t < NCO) ? coarseTot[t] : 0;
    s[t] = v;
    __syncthreads();
    #pragma unroll
    for (int off = 1; off < 256; off <<= 1) {
        int u = (t >= off) ? s[t - off] : 0;
        __syncthreads();
        s[t] += u;
        __syncthreads();
    }
    int excl = s[t] - v;
    if (t < NCO) { bucketBase[t] = excl; cursor[t] = excl; }
    if (t == 0) bucketBase[NCO] = NE;
}

// ---------------- pass 2: coarse bucketing; block reserves range via atomics ----
__global__ __launch_bounds__(256) void pass2_kernel(
    const int* __restrict__ eidx, const int* __restrict__ Hmat,
    int* __restrict__ cursor, int* __restrict__ ebuk)
{
    __shared__ int cur[NCO];
    int b = blockIdx.x, t = threadIdx.x;
    if (t < NCO) {
        int cnt = Hmat[t * P1B + b];
        cur[t] = atomicAdd(&cursor[t], cnt);
    }
    __syncthreads();
    int base = b * EPB;
    for (int e = base + t; e < base + EPB; e += 256) {
        int s = eidx[e];
        int d = eidx[NE + e];
        int pos = atomicAdd(&cur[d >> 8], 1);
        ebuk[pos] = ((d & 255) << 16) | s;
    }
}

// ---- qkv0 GEMM (blocks 0..624) + CSR pass 3 (blocks 625..781) -------------------
// Register double-buffered B staging: prefetch tile ct+1 into regs during ct's
// compute. qb rows: f16 [NN][128]. kvb rows: [k f16 (128)|v bf16 (128)], 512 B.
__global__ __launch_bounds__(256) void qkv0_p3_kernel(
    const float* __restrict__ Af, const unsigned short* __restrict__ BT,
    const float* __restrict__ bias,
    unsigned short* __restrict__ qb, unsigned short* __restrict__ kvb,
    const int* __restrict__ bucketBase, const int* __restrict__ ebuk,
    int* __restrict__ deg, int* __restrict__ offs, int* __restrict__ srcSorted)
{
    if (blockIdx.x >= GBLOCKS) {
        __shared__ int hist[256], loffs[256], cur[256];
        int c = blockIdx.x - GBLOCKS;
        int t = threadIdx.x;
        int base = bucketBase[c];
        int end = bucketBase[c + 1];
        hist[t] = 0;
        __syncthreads();
        for (int i = base + t; i < end; i += 256)
            atomicAdd(&hist[ebuk[i] >> 16], 1);
        __syncthreads();
        int v = hist[t];
        loffs[t] = v;
        __syncthreads();
        #pragma unroll
        for (int off = 1; off < 256; off <<= 1) {
            int u = (t >= off) ? loffs[t - off] : 0;
            __syncthreads();
            loffs[t] += u;
            __syncthreads();
        }
        int excl = loffs[t] - v;
        int n = c * 256 + t;
        if (n < NN) { deg[n] = v; offs[n] = base + excl; }
        cur[t] = excl;
        __syncthreads();
        for (int i = base + t; i < end; i += 256) {
            int p = ebuk[i];
            int pos = atomicAdd(&cur[p >> 16], 1);
            srcSorted[base + pos] = p & 0xffff;
        }
        return;
    }
    __shared__ unsigned short Bs[64][136];
    int t = threadIdx.x;
    int row0 = blockIdx.x * 64;
    int w = t >> 6;
    int lr = t & 15;
    int quad = (t & 63) >> 4;
    int row = row0 + w * 16 + lr;
    // staging address pattern (r_i, c8_i) for this thread
    int sr[4], sc[4];
    #pragma unroll
    for (int i = 0; i < 4; ++i) {
        int idx = t + i * 256;
        sr[i] = idx >> 4;
        sc[i] = (idx & 15) * 8;
    }

    frag8 af[4];
    {
        const float* ap = Af + (size_t)row * 128 + quad * 8;
        #pragma unroll
        for (int kc = 0; kc < 4; ++kc) {
            float4 a0 = *(const float4*)(ap + kc * 32);
            float4 a1 = *(const float4*)(ap + kc * 32 + 4);
            af[kc].u[0] = f2bf(a0.x); af[kc].u[1] = f2bf(a0.y);
            af[kc].u[2] = f2bf(a0.z); af[kc].u[3] = f2bf(a0.w);
            af[kc].u[4] = f2bf(a1.x); af[kc].u[5] = f2bf(a1.y);
            af[kc].u[6] = f2bf(a1.z); af[kc].u[7] = f2bf(a1.w);
        }
    }

    u16x8 pre[4];
    #pragma unroll
    for (int i = 0; i < 4; ++i)
        pre[i] = *(const u16x8*)(BT + (size_t)sr[i] * 128 + sc[i]);

    #pragma unroll
    for (int ct = 0; ct < 6; ++ct) {
        if (ct) __syncthreads();
        #pragma unroll
        for (int i = 0; i < 4; ++i) *(u16x8*)(&Bs[sr[i]][sc[i]]) = pre[i];
        __syncthreads();
        if (ct < 5) {
            #pragma unroll
            for (int i = 0; i < 4; ++i)
                pre[i] = *(const u16x8*)(BT + (size_t)((ct + 1) * 64 + sr[i]) * 128 + sc[i]);
        }
        f32x4 acc[4] = {{0.f,0.f,0.f,0.f},{0.f,0.f,0.f,0.f},
                        {0.f,0.f,0.f,0.f},{0.f,0.f,0.f,0.f}};
        #pragma unroll
        for (int kc = 0; kc < 4; ++kc) {
            #pragma unroll
            for (int n4 = 0; n4 < 4; ++n4) {
                short8 bfr = *(const short8*)(&Bs[n4 * 16 + lr][kc * 32 + quad * 8]);
                acc[n4] = __builtin_amdgcn_mfma_f32_16x16x32_bf16(bfr, af[kc].s, acc[n4], 0, 0, 0);
            }
        }
        unsigned short* dst = (ct < 2) ? (qb + (size_t)row * 128 + (ct & 1) * 64)
                                       : (kvb + (size_t)row * 256 + (ct - 2) * 64);
        #pragma unroll
        for (int n4 = 0; n4 < 4; ++n4) {
            int colb = n4 * 16 + quad * 4;
            float4 bv = *(const float4*)(bias + ct * 64 + colb);
            ushort4 o;
            if (ct >= 4) {
                o.x = f2bf(acc[n4][0] + bv.x);
                o.y = f2bf(acc[n4][1] + bv.y);
                o.z = f2bf(acc[n4][2] + bv.z);
                o.w = f2bf(acc[n4][3] + bv.w);
            } else {
                o.x = f2h(acc[n4][0] + bv.x);
                o.y = f2h(acc[n4][1] + bv.y);
                o.z = f2h(acc[n4][2] + bv.z);
                o.w = f2h(acc[n4][3] + bv.w);
            }
            *(ushort4*)(dst + colb) = o;
        }
    }
}

// Fused: out-GEMM (gelu(agg)@aWT + skip -> h) then second GEMM from h (in LDS).
// Register double-buffered B pipeline across all tile stages.
// HPFMT: 0 = Hprev f32, 1 = Hprev bf16.  P2: 0 = QKV out (store hb too), 2 = fc.
template <int HPFMT, int P2>
__global__ __launch_bounds__(256) void fused_kernel(
    const unsigned short* __restrict__ aggb,
    const unsigned short* __restrict__ aWT, const float* __restrict__ ab,
    const float* __restrict__ skip_p,
    const float* __restrict__ HprevF, const unsigned short* __restrict__ HprevB,
    unsigned short* __restrict__ hb_out,
    const unsigned short* __restrict__ W2T, const float* __restrict__ bias2,
    unsigned short* __restrict__ qb, unsigned short* __restrict__ kvb,
    float* __restrict__ outF)
{
    __shared__ unsigned short As[64][136];   // h tile handoff (wave-local rows)
    __shared__ unsigned short Bs[64][136];
    int t = threadIdx.x;
    int row0 = blockIdx.x * 64;
    int w = t >> 6;
    int lr = t & 15;
    int quad = (t & 63) >> 4;
    int row = row0 + w * 16 + lr;
    int sr[4], sc[4];
    #pragma unroll
    for (int i = 0; i < 4; ++i) {
        int idx = t + i * 256;
        sr[i] = idx >> 4;
        sc[i] = (idx & 15) * 8;
    }

    // phase-1 A fragments: gelu(aggb) direct to registers
    frag8 agf[4];
    {
        const unsigned short* ap = aggb + (size_t)row * 128 + quad * 8;
        #pragma unroll
        for (int kc = 0; kc < 4; ++kc) {
            u16x8 u = *(const u16x8*)(ap + kc * 32);
            #pragma unroll
            for (int j = 0; j < 8; ++j) agf[kc].u[j] = f2bf(gelu_tanh(bf2f(u[j])));
        }
    }

    float sv = skip_p[0];
    float beta = 1.f / (1.f + expf(-sv));
    float omb = 1.f - beta;

    u16x8 pre[4];
    #pragma unroll
    for (int i = 0; i < 4; ++i)
        pre[i] = *(const u16x8*)(aWT + (size_t)sr[i] * 128 + sc[i]);

    // phase 1: h-acc over 2 aWT tiles
    f32x4 hacc[2][4];
    #pragma unroll
    for (int ct = 0; ct < 2; ++ct) {
        if (ct) __syncthreads();
        #pragma unroll
        for (int i = 0; i < 4; ++i) *(u16x8*)(&Bs[sr[i]][sc[i]]) = pre[i];
        __syncthreads();
        {   // prefetch next stage: aWT tile1, then first phase-2 tile
            const unsigned short* nxt = (ct == 0) ? (aWT + (size_t)64 * 128) : W2T;
            #pragma unroll
            for (int i = 0; i < 4; ++i)
                pre[i] = *(const u16x8*)(nxt + (size_t)sr[i] * 128 + sc[i]);
        }
        #pragma unroll
        for (int n4 = 0; n4 < 4; ++n4) hacc[ct][n4] = (f32x4){0.f,0.f,0.f,0.f};
        #pragma unroll
        for (int kc = 0; kc < 4; ++kc) {
            #pragma unroll
            for (int n4 = 0; n4 < 4; ++n4) {
                short8 bfr = *(const short8*)(&Bs[n4 * 16 + lr][kc * 32 + quad * 8]);
                hacc[ct][n4] = __builtin_amdgcn_mfma_f32_16x16x32_bf16(bfr, agf[kc].s, hacc[ct][n4], 0, 0, 0);
            }
        }
    }

    // epilogue: h = relu(beta*(.)+ (1-beta)*Hprev) -> As (wave-local rows)
    #pragma unroll
    for (int ct = 0; ct < 2; ++ct) {
        #pragma unroll
        for (int n4 = 0; n4 < 4; ++n4) {
            int colb = ct * 64 + n4 * 16 + quad * 4;
            float4 bv = *(const float4*)(ab + colb);
            float hp[4];
            if (HPFMT == 0) {
                float4 h4 = *(const float4*)(HprevF + (size_t)row * 128 + colb);
                hp[0] = h4.x; hp[1] = h4.y; hp[2] = h4.z; hp[3] = h4.w;
            } else {
                ushort4 h4 = *(const ushort4*)(HprevB + (size_t)row * 128 + colb);
                hp[0] = bf2f(h4.x); hp[1] = bf2f(h4.y); hp[2] = bf2f(h4.z); hp[3] = bf2f(h4.w);
            }
            ushort4 o;
            o.x = f2bf(fmaxf(beta * (hacc[ct][n4][0] + bv.x) + omb * hp[0], 0.f));
            o.y = f2bf(fmaxf(beta * (hacc[ct][n4][1] + bv.y) + omb * hp[1], 0.f));
            o.z = f2bf(fmaxf(beta * (hacc[ct][n4][2] + bv.z) + omb * hp[2], 0.f));
            o.w = f2bf(fmaxf(beta * (hacc[ct][n4][3] + bv.w) + omb * hp[3], 0.f));
            *(ushort4*)(&As[w * 16 + lr][colb]) = o;
            if (P2 == 0) *(ushort4*)(hb_out + (size_t)row * 128 + colb) = o;
        }
    }

    if (P2 == 0) {
        #pragma unroll
        for (int ct = 0; ct < 6; ++ct) {
            __syncthreads();
            #pragma unroll
            for (int i = 0; i < 4; ++i) *(u16x8*)(&Bs[sr[i]][sc[i]]) = pre[i];
            __syncthreads();
            if (ct < 5) {
                #pragma unroll
                for (int i = 0; i < 4; ++i)
                    pre[i] = *(const u16x8*)(W2T + (size_t)((ct + 1) * 64 + sr[i]) * 128 + sc[i]);
            }
            f32x4 acc[4] = {{0.f,0.f,0.f,0.f},{0.f,0.f,0.f,0.f},
                            {0.f,0.f,0.f,0.f},{0.f,0.f,0.f,0.f}};
            #pragma unroll
            for (int kc = 0; kc < 4; ++kc) {
                short8 afr = *(const short8*)(&As[w * 16 + lr][kc * 32 + quad * 8]);
                #pragma unroll
                for (int n4 = 0; n4 < 4; ++n4) {
                    short8 bfr = *(const short8*)(&Bs[n4 * 16 + lr][kc * 32 + quad * 8]);
                    acc[n4] = __builtin_amdgcn_mfma_f32_16x16x32_bf16(bfr, afr, acc[n4], 0, 0, 0);
                }
            }
            unsigned short* dst = (ct < 2) ? (qb + (size_t)row * 128 + (ct & 1) * 64)
                                           : (kvb + (size_t)row * 256 + (ct - 2) * 64);
            #pragma unroll
            for (int n4 = 0; n4 < 4; ++n4) {
                int colb = n4 * 16 + quad * 4;
                float4 bv = *(const float4*)(bias2 + ct * 64 + colb);
                ushort4 o;
                if (ct >= 4) {
                    o.x = f2bf(acc[n4][0] + bv.x);
                    o.y = f2bf(acc[n4][1] + bv.y);
                    o.z = f2bf(acc[n4][2] + bv.z);
                    o.w = f2bf(acc[n4][3] + bv.w);
                } else {
                    o.x = f2h(acc[n4][0] + bv.x);
                    o.y = f2h(acc[n4][1] + bv.y);
                    o.z = f2h(acc[n4][2] + bv.z);
                    o.w = f2h(acc[n4][3] + bv.w);
                }
                *(ushort4*)(dst + colb) = o;
            }
        }
    } else {
        __syncthreads();
        #pragma unroll
        for (int i = 0; i < 4; ++i) *(u16x8*)(&Bs[sr[i]][sc[i]]) = pre[i];
        __syncthreads();
        f32x4 acc[4] = {{0.f,0.f,0.f,0.f},{0.f,0.f,0.f,0.f},
                        {0.f,0.f,0.f,0.f},{0.f,0.f,0.f,0.f}};
        #pragma unroll
        for (int kc = 0; kc < 4; ++kc) {
            short8 afr = *(const short8*)(&As[w * 16 + lr][kc * 32 + quad * 8]);
            #pragma unroll
            for (int n4 = 0; n4 < 4; ++n4) {
                short8 bfr = *(const short8*)(&Bs[n4 * 16 + lr][kc * 32 + quad * 8]);
                acc[n4] = __builtin_amdgcn_mfma_f32_16x16x32_bf16(bfr, afr, acc[n4], 0, 0, 0);
            }
        }
        #pragma unroll
        for (int n4 = 0; n4 < 4; ++n4) {
            int colb = n4 * 16 + quad * 4;
            float4 bv = *(const float4*)(bias2 + colb);
            float4 o;
            o.x = acc[n4][0] + bv.x;
            o.y = acc[n4][1] + bv.y;
            o.z = acc[n4][2] + bv.z;
            o.w = acc[n4][3] + bv.w;
            *(float4*)(outF + (size_t)row * 64 + colb) = o;
        }
    }
}

// ---------------- Fused per-destination softmax + aggregation --------------------
__global__ __launch_bounds__(256) void aggregate_kernel(
    const unsigned short* __restrict__ qb, const unsigned short* __restrict__ kvb,
    const int* __restrict__ deg, const int* __restrict__ offs,
    const int* __restrict__ srcSorted, unsigned short* __restrict__ aggb)
{
    int n = (blockIdx.x * 256 + threadIdx.x) >> 6;
    int lane = threadIdx.x & 63;
    int es = lane >> 3;
    int h = lane & 7;

#if HAS_FDOT2
    h16x2 q2[8];
    {
        const h16x2* qp = (const h16x2*)(qb + (size_t)n * 128 + h * 16);
        #pragma unroll
        for (int j = 0; j < 8; ++j) q2[j] = qp[j];
    }
#else
    float q[16];
    {
        kv8 a, b;
        a.u = *(const u16x8*)(qb + (size_t)n * 128 + h * 16);
        b.u = *(const u16x8*)(qb + (size_t)n * 128 + h * 16 + 8);
        #pragma unroll
        for (int j = 0; j < 8; ++j) { q[j] = (float)a.h[j]; q[8 + j] = (float)b.h[j]; }
    }
#endif
    float acc[16];
    #pragma unroll
    for (int j = 0; j < 16; ++j) acc[j] = 0.f;
    float den = 0.f;

    int start = offs[n];
    int d = deg[n];
    if (d > 0) {
        int ng = (d + 7) >> 3;
        int lastIdx = start + d - 1;

        kv8 ka0, ka1; u16x8 vA0, vA1;
        kv8 kB0, kB1; u16x8 vB0, vB1;
        {
            int i0 = start + es; if (i0 > lastIdx) i0 = lastIdx;
            const unsigned short* p = kvb + (size_t)srcSorted[i0] * 256 + h * 16;
            ka0.u = *(const u16x8*)p;        ka1.u = *(const u16x8*)(p + 8);
            vA0 = *(const u16x8*)(p + 128);  vA1 = *(const u16x8*)(p + 136);
        }
        kB0 = ka0; kB1 = ka1; vB0 = vA0; vB1 = vA1;
        if (ng > 1) {
            int i1 = start + 8 + es; if (i1 > lastIdx) i1 = lastIdx;
            const unsigned short* p = kvb + (size_t)srcSorted[i1] * 256 + h * 16;
            kB0.u = *(const u16x8*)p;        kB1.u = *(const u16x8*)(p + 8);
            vB0 = *(const u16x8*)(p + 128);  vB1 = *(const u16x8*)(p + 136);
        }

        for (int g = 0; g < ng; ++g) {
            kv8 kC0 = ka0, kC1 = ka1; u16x8 vC0 = vA0, vC1 = vA1;
            if (g + 2 < ng) {
                int ni = start + (g + 2) * 8 + es; if (ni > lastIdx) ni = lastIdx;
                const unsigned short* p = kvb + (size_t)srcSorted[ni] * 256 + h * 16;
                kC0.u = *(const u16x8*)p;        kC1.u = *(const u16x8*)(p + 8);
                vC0 = *(const u16x8*)(p + 128);  vC1 = *(const u16x8*)(p + 136);
            }
            float pdot = 0.f;
#if HAS_FDOT2
            #pragma unroll
            for (int j = 0; j < 4; ++j) pdot = __builtin_amdgcn_fdot2(ka0.p[j], q2[j], pdot, false);
            #pragma unroll
            for (int j = 0; j < 4; ++j) pdot = __builtin_amdgcn_fdot2(ka1.p[j], q2[4 + j], pdot, false);
#else
            #pragma unroll
            for (int j = 0; j < 8; ++j) pdot = fmaf((float)ka0.h[j], q[j], pdot);
            #pragma unroll
            for (int j = 0; j < 8; ++j) pdot = fmaf((float)ka1.h[j], q[8 + j], pdot);
#endif
            float ev = (g * 8 + es < d) ? exp2f(pdot) : 0.f;
            den += ev;
            float vf[16];
            unpack8(vA0, vf); unpack8(vA1, vf + 8);
            #pragma unroll
            for (int j = 0; j < 16; ++j) acc[j] = fmaf(vf[j], ev, acc[j]);
            ka0 = kB0; ka1 = kB1; vA0 = vB0; vA1 = vB1;
            kB0 = kC0; kB1 = kC1; vB0 = vC0; vB1 = vC1;
        }
    }
    #pragma unroll
    for (int m = 8; m < 64; m <<= 1) {
        den += __shfl_xor(den, m, 64);
        #pragma unroll
        for (int j = 0; j < 16; ++j) acc[j] += __shfl_xor(acc[j], m, 64);
    }
    if (es == 0) {
        float w = 1.f / (den + 1e-16f);
        u16x8 o0, o1;
        #pragma unroll
        for (int j = 0; j < 8; ++j) {
            o0[j] = f2bf(acc[j] * w);
            o1[j] = f2bf(acc[j + 8] * w);
        }
        *(u16x8*)(aggb + (size_t)n * 128 + h * 16) = o0;
        *(u16x8*)(aggb + (size_t)n * 128 + h * 16 + 8) = o1;
    }
}

extern "C" void kernel_launch(void* const* d_in, const int* in_sizes, int n_in,
                              void* d_out, int out_size, void* d_ws, size_t ws_size,
                              hipStream_t stream) {
    const float* x     = (const float*)d_in[0];
    const int*   eidx  = (const int*)d_in[1];
    const float* Wk    = (const float*)d_in[2];
    const float* bk    = (const float*)d_in[3];
    const float* Wq    = (const float*)d_in[4];
    const float* bq    = (const float*)d_in[5];
    const float* Wv    = (const float*)d_in[6];
    const float* bv    = (const float*)d_in[7];
    const float* a_rel = (const float*)d_in[8];
    const float* m_rel = (const float*)d_in[9];
    const float* p_rel = (const float*)d_in[10];
    const float* skip  = (const float*)d_in[11];
    const float* aW    = (const float*)d_in[12];
    const float* ab    = (const float*)d_in[13];
    const float* fcW   = (const float*)d_in[14];
    const float* fcb   = (const float*)d_in[15];
    float* out = (float*)d_out;

    float* biasf = (float*)d_ws;                              // 2*384
    unsigned short* hb   = (unsigned short*)(biasf + 768);    // NN*128
    unsigned short* qb   = hb + (size_t)NN * 128;             // NN*128 (f16)
    unsigned short* kvb  = qb + (size_t)NN * 128;             // NN*256 ([k f16|v bf16])
    unsigned short* aggb = kvb + (size_t)NN * 256;            // NN*128
    unsigned short* BfT  = aggb + (size_t)NN * 128;           // 2*384*128
    unsigned short* aWT  = BfT + 2 * 384 * 128;               // 2*128*128
    unsigned short* fcWT = aWT + 2 * 128 * 128;               // 64*128
    int* deg        = (int*)(fcWT + 64 * 128);                // NN
    int* offs       = deg + NN;                               // NN
    int* Hmat       = offs + NN;                              // NCO*P1B
    int* coarseTot  = Hmat + NCO * P1B;                       // NCO
    int* bucketBase = coarseTot + NCO;                        // NCO+1
    int* cursor     = bucketBase + NCO + 1;                   // NCO
    int* ebuk       = cursor + NCO;                           // NE
    int* srcSorted  = ebuk + NE;                              // NE

    hipMemsetAsync(coarseTot, 0, NCO * sizeof(int), stream);
    prep_kernel<<<WBLOCKS + P1B, 256, 0, stream>>>(
        Wq, bq, Wk, bk, a_rel, Wv, bv, m_rel, p_rel, aW, fcW,
        BfT, biasf, aWT, fcWT, eidx, Hmat, coarseTot);
    scan157_kernel<<<1, 256, 0, stream>>>(coarseTot, bucketBase, cursor);
    pass2_kernel<<<P1B, 256, 0, stream>>>(eidx, Hmat, cursor, ebuk);

    // ---- layer 0 QKV + CSR pass 3 (co-scheduled) ----
    qkv0_p3_kernel<<<GBLOCKS + NCO, 256, 0, stream>>>(
        x, BfT, biasf, qb, kvb, bucketBase, ebuk, deg, offs, srcSorted);
    aggregate_kernel<<<NN / 4, 256, 0, stream>>>(qb, kvb, deg, offs, srcSorted, aggb);

    // ---- fused: out-GEMM(0) -> h0 -> QKV(1) ----
    fused_kernel<0, 0><<<GBLOCKS, 256, 0, stream>>>(
        aggb, aWT, ab, skip, x, nullptr, hb,
        BfT + 49152, biasf + 384, qb, kvb, nullptr);
    aggregate_kernel<<<NN / 4, 256, 0, stream>>>(qb, kvb, deg, offs, srcSorted, aggb);

    // ---- fused: out-GEMM(1) -> h1 (LDS) -> fc ----
    fused_kernel<1, 2><<<GBLOCKS, 256, 0, stream>>>(
        aggb, aWT + 16384, ab + 128, skip + 1, nullptr, hb, nullptr,
        fcWT, fcb, nullptr, nullptr, out);
}